// Round 4
// baseline (240.332 us; speedup 1.0000x reference)
//
#include <hip/hip_runtime.h>
#include <hip/hip_bf16.h>

#define SEQ 1024
#define DIM 128
#define NEG_SLOPE 0.1f

typedef __bf16 bf16x8 __attribute__((ext_vector_type(8)));
typedef float f32x4v __attribute__((ext_vector_type(4)));

__device__ __forceinline__ unsigned short bfb(float f) {
    __bf16 h = (__bf16)f;
    return __builtin_bit_cast(unsigned short, h);
}
__device__ __forceinline__ unsigned mpack(int x0, int x1) {
    unsigned m0 = (x0 != 0) ? 0x3F80u : 0u;   // bf16 1.0
    unsigned m1 = (x1 != 0) ? 0x3F80u : 0u;
    return m0 | (m1 << 16);
}
// XOR-swizzle unit permutation: distinct over x=0..7, spreads 16B units
__device__ __forceinline__ int fxv(int x) {
    return ((x & 3) | ((x & 1) << 2)) ^ ((x >> 2) & 7);
}
// Raw barrier: LDS-drain only (no vmcnt(0) drain -> register prefetch stays in flight)
__device__ __forceinline__ void bar() {
    asm volatile("s_waitcnt lgkmcnt(0)" ::: "memory");
    __builtin_amdgcn_s_barrier();
    __builtin_amdgcn_sched_barrier(0);
}

// ---------------- pre-kernel 1: W,B -> transposed bf16 [n][k] ----------------
__global__ __launch_bounds__(256)
void wb_t(const float* __restrict__ W, const float* __restrict__ Bm,
          unsigned short* __restrict__ WT, unsigned short* __restrict__ BT) {
    const int gid = blockIdx.x * 256 + threadIdx.x;   // grid 64 -> 16384 = 128*128
    const int n = gid >> 7, k = gid & 127;
    WT[gid] = bfb(W[k * DIM + n]);
    BT[gid] = bfb(Bm[k * DIM + n]);
}

// ---------------- pre-kernel 2: nodes [b][o][d] f32 -> nodesT [b][d][o] bf16 --
__global__ __launch_bounds__(256)
void nodes_t_kernel(const float* __restrict__ nodes, unsigned short* __restrict__ nodesT) {
    // grid 512 = 32 batches x 16 o-tiles of 64
    const int b  = blockIdx.x >> 4;
    const int o0 = (blockIdx.x & 15) << 6;
    __shared__ unsigned short T[DIM][66];   // 132B rows: stride 33 words -> conflict-lite

    const float* src = nodes + (size_t)b * SEQ * DIM;
    const int t = threadIdx.x & 31;         // d-quad: d = 4t+j
    const int g = threadIdx.x >> 5;         // o-octet: o = g*8+r

    float4 v[8];
    #pragma unroll
    for (int r = 0; r < 8; ++r)
        v[r] = *(const float4*)(src + (size_t)(o0 + g * 8 + r) * DIM + 4 * t);
    #pragma unroll
    for (int j = 0; j < 4; ++j) {
        #pragma unroll
        for (int p = 0; p < 4; ++p) {
            unsigned w = (unsigned)bfb(((const float*)&v[2 * p])[j]) |
                         ((unsigned)bfb(((const float*)&v[2 * p + 1])[j]) << 16);
            *(unsigned*)((unsigned char*)&T[0][0] + (size_t)(4 * t + j) * 132 + (g * 8 + 2 * p) * 2) = w;
        }
    }
    __syncthreads();
    // store: thread -> (d = tid>>1, o-half h), 64B per thread, coalesced-ish dwordx4
    const int d = threadIdx.x >> 1, h = threadIdx.x & 1;
    unsigned u[16];
    #pragma unroll
    for (int s = 0; s < 16; ++s)
        u[s] = *(const unsigned*)((const unsigned char*)&T[0][0] + (size_t)d * 132 + h * 64 + s * 4);
    unsigned short* dst = nodesT + (size_t)b * DIM * SEQ + (size_t)d * SEQ + o0 + h * 32;
    #pragma unroll
    for (int s = 0; s < 4; ++s) {
        uint4 q = make_uint4(u[4 * s], u[4 * s + 1], u[4 * s + 2], u[4 * s + 3]);
        *(uint4*)((unsigned char*)dst + s * 16) = q;
    }
}

// ---------------- main kernel: 32-row i-tile, mask-only LDS staging ----------
__global__ __launch_bounds__(256, 4)
void gcn_fused(const float* __restrict__ nodes,
               const int* __restrict__ adj,
               const unsigned short* __restrict__ nodesT,
               const unsigned short* __restrict__ WT,
               const unsigned short* __restrict__ BT,
               float* __restrict__ out)
{
    __shared__ union {
        unsigned char  m[2][4096];          // dbuf mask_t[32 i][64 o] bf16, 128B rows
        unsigned short pooled[32][136];     // phase-2 A operand
    } u;

    // XCD swizzle: 32 i-tiles of a batch land on one XCD (nodesT/adj L2 locality)
    const int bid   = blockIdx.x;           // grid 1024 = 4 blocks/CU, fully resident
    const int xcd   = bid & 7;
    const int slot  = bid >> 3;
    const int batch = ((slot >> 5) << 3) | xcd;   // [0,32)
    const int itile = slot & 31;
    const int i0    = itile << 5;

    const int tid  = threadIdx.x;
    const int wave = tid >> 6;              // 0..3 -> d 32-block
    const int lane = tid & 63;
    const int lrow = lane & 15;
    const int quad = lane >> 4;

    const int*            __restrict__ adj_b   = adj    + (size_t)batch * SEQ * SEQ;
    const float*          __restrict__ nodes_b = nodes  + (size_t)batch * SEQ * DIM;
    const unsigned short* __restrict__ nT_b    = nodesT + (size_t)batch * DIM * SEQ;

    // staging mapping: thread -> o-pair (2*tq), i-quad (4*ic)
    const int tq   = tid >> 3;              // 0..31
    const int ic   = tid & 7;               // 0..7
    const int fxic = fxv(ic);
    const int gi0  = i0 + 4 * ic;
    const int o0   = 2 * tq;

    const int fx0 = fxv(lrow >> 2);         // compute-side swizzle (mf=0 rows)
    const int fx1 = fxv(4 + (lrow >> 2));   // (mf=1 rows)

    f32x4v acc[2][2] = {};
    f32x4v acc_cnt[2] = {};
    bf16x8 ones;
    #pragma unroll
    for (int j = 0; j < 8; ++j) ones[j] = __builtin_bit_cast(__bf16, (unsigned short)0x3F80);

    int4   A0[2], A1[2];                    // adj register staging (2-chunk deep)
    bf16x8 bvA[4], bvB[4];                  // nodesT B-fragments (1-chunk deep)

    auto load_adj = [&](int c, int4 (&A)[2]) {
        const int* pa = adj_b + (size_t)(c * 64 + o0) * SEQ + gi0;
        A[0] = *(const int4*)pa;
        A[1] = *(const int4*)(pa + SEQ);
    };
    auto load_bv = [&](int c, bf16x8 (&bv)[4]) {
        const unsigned short* pn = nT_b + (size_t)(wave * 32 + lrow) * SEQ + c * 64 + quad * 8;
        bv[0] = *(const bf16x8*)(pn);                 // kk0,nf0
        bv[1] = *(const bf16x8*)(pn + 16 * SEQ);      // kk0,nf1
        bv[2] = *(const bf16x8*)(pn + 32);            // kk1,nf0
        bv[3] = *(const bf16x8*)(pn + 16 * SEQ + 32); // kk1,nf1
    };
    auto write_mask = [&](int b, const int4 (&A)[2]) {
        unsigned char* mb = u.m[b];
        #pragma unroll
        for (int j = 0; j < 4; ++j) {
            unsigned w = mpack(((const int*)&A[0])[j], ((const int*)&A[1])[j]);
            *(unsigned*)(mb + (4 * ic + j) * 128 + (((tq >> 2) ^ fxic) << 4) + 4 * (tq & 3)) = w;
        }
    };
    auto compute = [&](int b, const bf16x8 (&bv)[4]) {
        const unsigned char* mb = u.m[b];
        #pragma unroll
        for (int kk = 0; kk < 2; ++kk) {
            bf16x8 av0 = *(const bf16x8*)(mb + lrow * 128        + (((4 * kk + quad) ^ fx0) << 4));
            bf16x8 av1 = *(const bf16x8*)(mb + (16 + lrow) * 128 + (((4 * kk + quad) ^ fx1) << 4));
            acc[0][0] = __builtin_amdgcn_mfma_f32_16x16x32_bf16(av0, bv[2 * kk + 0], acc[0][0], 0, 0, 0);
            acc[0][1] = __builtin_amdgcn_mfma_f32_16x16x32_bf16(av0, bv[2 * kk + 1], acc[0][1], 0, 0, 0);
            acc[1][0] = __builtin_amdgcn_mfma_f32_16x16x32_bf16(av1, bv[2 * kk + 0], acc[1][0], 0, 0, 0);
            acc[1][1] = __builtin_amdgcn_mfma_f32_16x16x32_bf16(av1, bv[2 * kk + 1], acc[1][1], 0, 0, 0);
            acc_cnt[0] = __builtin_amdgcn_mfma_f32_16x16x32_bf16(av0, ones, acc_cnt[0], 0, 0, 0);
            acc_cnt[1] = __builtin_amdgcn_mfma_f32_16x16x32_bf16(av1, ones, acc_cnt[1], 0, 0, 0);
        }
    };

    // prologue: 2-deep adj, 1-deep bv
    load_adj(0, A0); load_adj(1, A1);
    load_bv(0, bvA); load_bv(1, bvB);
    write_mask(0, A0);
    load_adj(2, A0);
    bar();

    for (int cc = 0; cc < 8; ++cc) {
        const int c0 = 2 * cc;
        compute(0, bvA);
        write_mask(1, A1);
        if (c0 + 3 < 16) load_adj(c0 + 3, A1);
        if (c0 + 2 < 16) load_bv(c0 + 2, bvA);
        bar();
        compute(1, bvB);
        if (c0 + 2 < 16) write_mask(0, A0);
        if (c0 + 4 < 16) load_adj(c0 + 4, A0);
        if (c0 + 3 < 16) load_bv(c0 + 3, bvB);
        bar();
    }

    // poolsum -> pooled (divide by MFMA-computed in-degree)
    #pragma unroll
    for (int mf = 0; mf < 2; ++mf) {
        #pragma unroll
        for (int r = 0; r < 4; ++r) {
            const int row = mf * 16 + quad * 4 + r;
            const float cnt = acc_cnt[mf][r];
            const float inv = (cnt > 0.5f) ? 1.0f / cnt : 0.0f;
            #pragma unroll
            for (int nf = 0; nf < 2; ++nf)
                u.pooled[row][wave * 32 + nf * 16 + lrow] = bfb(acc[mf][nf][r] * inv);
        }
    }
    bar();

    f32x4v acc2[2][2] = {};
    const int dn = wave * 32 + lrow;

    // pooled @ W  (K=128), bv from WT[n][k] bf16: 1 dwordx4 per frag per lane
    #pragma unroll
    for (int ks = 0; ks < 4; ++ks) {
        const int k0 = ks * 32 + quad * 8;
        bf16x8 av[2], bv2[2];
        #pragma unroll
        for (int mf = 0; mf < 2; ++mf)
            av[mf] = *(const bf16x8*)((const unsigned char*)&u.pooled[0][0] + (mf * 16 + lrow) * 272 + k0 * 2);
        #pragma unroll
        for (int nf = 0; nf < 2; ++nf)
            bv2[nf] = *(const bf16x8*)(WT + (size_t)(dn + nf * 16) * DIM + k0);
        #pragma unroll
        for (int mf = 0; mf < 2; ++mf)
            #pragma unroll
            for (int nf = 0; nf < 2; ++nf)
                acc2[mf][nf] = __builtin_amdgcn_mfma_f32_16x16x32_bf16(av[mf], bv2[nf], acc2[mf][nf], 0, 0, 0);
    }
    // nodes @ B  (K=128)
    #pragma unroll
    for (int ks = 0; ks < 4; ++ks) {
        const int k0 = ks * 32 + quad * 8;
        bf16x8 av[2], bv2[2];
        #pragma unroll
        for (int mf = 0; mf < 2; ++mf) {
            const float* p = nodes_b + (size_t)(i0 + mf * 16 + lrow) * DIM + k0;
            const float4 f1 = *(const float4*)p;
            const float4 f2 = *(const float4*)(p + 4);
            av[mf][0] = (__bf16)f1.x; av[mf][1] = (__bf16)f1.y;
            av[mf][2] = (__bf16)f1.z; av[mf][3] = (__bf16)f1.w;
            av[mf][4] = (__bf16)f2.x; av[mf][5] = (__bf16)f2.y;
            av[mf][6] = (__bf16)f2.z; av[mf][7] = (__bf16)f2.w;
        }
        #pragma unroll
        for (int nf = 0; nf < 2; ++nf)
            bv2[nf] = *(const bf16x8*)(BT + (size_t)(dn + nf * 16) * DIM + k0);
        #pragma unroll
        for (int mf = 0; mf < 2; ++mf)
            #pragma unroll
            for (int nf = 0; nf < 2; ++nf)
                acc2[mf][nf] = __builtin_amdgcn_mfma_f32_16x16x32_bf16(av[mf], bv2[nf], acc2[mf][nf], 0, 0, 0);
    }

    // leaky-relu + store
    float* out_b = out + (size_t)batch * SEQ * DIM;
    #pragma unroll
    for (int mf = 0; mf < 2; ++mf) {
        #pragma unroll
        for (int nf = 0; nf < 2; ++nf) {
            const int col = wave * 32 + nf * 16 + lrow;
            #pragma unroll
            for (int r = 0; r < 4; ++r) {
                const int row = i0 + mf * 16 + quad * 4 + r;
                const float x = acc2[mf][nf][r];
                out_b[(size_t)row * DIM + col] = (x > 0.0f) ? x : NEG_SLOPE * x;
            }
        }
    }
}

// ---------------- fallback (round-2 kernel, verbatim) if workspace too small --
#define BUF_STRIDE 24576
#define NODES_OFF  8192
__device__ __forceinline__ int fb_swz(int row, int unit) {
    const int x  = row >> 2;
    const int fx = ((x & 3) | ((x & 1) << 2)) ^ ((x >> 2) & 7);
    return row * 128 + ((unit ^ fx) << 4);
}
__global__ __launch_bounds__(256, 2)
void gcn_fused_fb(const float* __restrict__ nodes, const int* __restrict__ adj,
                  const float* __restrict__ W, const float* __restrict__ Bm,
                  float* __restrict__ out)
{
    __shared__ alignas(16) unsigned char lds[2 * BUF_STRIDE];
    const int bid = blockIdx.x, xcd = bid & 7, slot = bid >> 3;
    const int batch = ((slot >> 4) << 3) | xcd, mtile = slot & 15, i0 = mtile << 6;
    const int tid = threadIdx.x, wave = tid >> 6, lane = tid & 63;
    const int wm = wave >> 1, wn = wave & 1, lrow = lane & 15, quad = lane >> 4;
    const int* __restrict__ adj_b = adj + (size_t)batch * SEQ * SEQ;
    const float* __restrict__ nodes_b = nodes + (size_t)batch * SEQ * DIM;
    const int a_row = (tid >> 4) * 4, a_col = (tid & 15) * 4;
    const int n_row = (tid >> 5) * 4, n_col = (tid & 31) * 4;
    const int m_unit = (tid >> 4) >> 1, m_sub = ((tid >> 4) & 1) * 8;
    const int n_unit = (tid >> 5) >> 1, n_sub = ((tid >> 5) & 1) * 8;
    f32x4v acc[2][4] = {}; f32x4v acc_cnt[2] = {};
    bf16x8 ones;
    #pragma unroll
    for (int j = 0; j < 8; ++j) ones[j] = __builtin_bit_cast(__bf16, (unsigned short)0x3F80);
    int4 A0[4], A1[4]; float4 N0[8], N1[8];
    auto load_chunk = [&](int o0, int4 (&A)[4], float4 (&N)[8]) {
        const int* pa = adj_b + (size_t)(o0 + a_row) * SEQ + (i0 + a_col);
        #pragma unroll
        for (int r = 0; r < 4; ++r) A[r] = *(const int4*)(pa + (size_t)r * SEQ);
        const float* pn = nodes_b + (size_t)(o0 + n_row) * DIM + n_col;
        #pragma unroll
        for (int it = 0; it < 2; ++it)
            #pragma unroll
            for (int r = 0; r < 4; ++r)
                N[it * 4 + r] = *(const float4*)(pn + (size_t)(it * 32 + r) * DIM);
    };
    auto write_lds = [&](int base, const int4 (&A)[4], const float4 (&N)[8]) {
        unsigned char* mb = lds + base; unsigned char* nb = lds + base + NODES_OFF;
        #pragma unroll
        for (int j = 0; j < 4; ++j) {
            uint2 w;
            w.x = mpack(((const int*)&A[0])[j], ((const int*)&A[1])[j]);
            w.y = mpack(((const int*)&A[2])[j], ((const int*)&A[3])[j]);
            *(uint2*)(mb + fb_swz(a_col + j, m_unit) + m_sub) = w;
        }
        #pragma unroll
        for (int it = 0; it < 2; ++it) {
            #pragma unroll
            for (int j = 0; j < 4; ++j) {
                uint2 w;
                w.x = (unsigned)bfb(((const float*)&N[it*4+0])[j]) | ((unsigned)bfb(((const float*)&N[it*4+1])[j]) << 16);
                w.y = (unsigned)bfb(((const float*)&N[it*4+2])[j]) | ((unsigned)bfb(((const float*)&N[it*4+3])[j]) << 16);
                *(uint2*)(nb + fb_swz(n_col + j, 4 * it + n_unit) + n_sub) = w;
            }
        }
    };
    auto compute = [&](int base) {
        const unsigned char* mb = lds + base; const unsigned char* nb = lds + base + NODES_OFF;
        #pragma unroll
        for (int kk = 0; kk < 2; ++kk) {
            bf16x8 av[2], bv[4];
            av[0] = *(const bf16x8*)(mb + fb_swz(wm * 32 + lrow, 4 * kk + quad));
            av[1] = *(const bf16x8*)(mb + fb_swz(wm * 32 + 16 + lrow, 4 * kk + quad));
            #pragma unroll
            for (int nf = 0; nf < 4; ++nf)
                bv[nf] = *(const bf16x8*)(nb + fb_swz(wn * 64 + nf * 16 + lrow, 4 * kk + quad));
            #pragma unroll
            for (int mf = 0; mf < 2; ++mf) {
                #pragma unroll
                for (int nf = 0; nf < 4; ++nf)
                    acc[mf][nf] = __builtin_amdgcn_mfma_f32_16x16x32_bf16(av[mf], bv[nf], acc[mf][nf], 0, 0, 0);
                acc_cnt[mf] = __builtin_amdgcn_mfma_f32_16x16x32_bf16(av[mf], ones, acc_cnt[mf], 0, 0, 0);
            }
        }
    };
    load_chunk(0, A0, N0); load_chunk(64, A1, N1);
    write_lds(0, A0, N0); load_chunk(128, A0, N0); bar();
    for (int cc = 0; cc < 8; ++cc) {
        const int c0 = cc * 2;
        compute(0); write_lds(BUF_STRIDE, A1, N1);
        if (c0 + 3 < 16) load_chunk((c0 + 3) * 64, A1, N1);
        bar();
        compute(BUF_STRIDE);
        if (c0 + 2 < 16) write_lds(0, A0, N0);
        if (c0 + 4 < 16) load_chunk((c0 + 4) * 64, A0, N0);
        bar();
    }
    unsigned short (*pooled)[136] = (unsigned short (*)[136])(void*)lds;
    #pragma unroll
    for (int mf = 0; mf < 2; ++mf)
        #pragma unroll
        for (int r = 0; r < 4; ++r) {
            const int row = wm * 32 + mf * 16 + quad * 4 + r;
            const float cnt = acc_cnt[mf][r];
            const float inv = (cnt > 0.5f) ? 1.0f / cnt : 0.0f;
            #pragma unroll
            for (int nf = 0; nf < 4; ++nf)
                pooled[row][wn * 64 + nf * 16 + lrow] = bfb(acc[mf][nf][r] * inv);
        }
    __syncthreads();
    f32x4v acc2[2][4] = {};
    const int d_b0 = wn * 64 + lrow;
    #pragma unroll
    for (int ks = 0; ks < 4; ++ks) {
        const int k0 = ks * 32 + quad * 8;
        bf16x8 av[2];
        #pragma unroll
        for (int mf = 0; mf < 2; ++mf)
            av[mf] = *(const bf16x8*)&pooled[wm * 32 + mf * 16 + lrow][k0];
        bf16x8 bv[4];
        const float* pw = W + (size_t)k0 * DIM + d_b0;
        #pragma unroll
        for (int nf = 0; nf < 4; ++nf)
            #pragma unroll
            for (int j = 0; j < 8; ++j) bv[nf][j] = (__bf16)pw[j * DIM + nf * 16];
        #pragma unroll
        for (int mf = 0; mf < 2; ++mf)
            #pragma unroll
            for (int nf = 0; nf < 4; ++nf)
                acc2[mf][nf] = __builtin_amdgcn_mfma_f32_16x16x32_bf16(av[mf], bv[nf], acc2[mf][nf], 0, 0, 0);
    }
    #pragma unroll
    for (int ks = 0; ks < 4; ++ks) {
        const int k0 = ks * 32 + quad * 8;
        bf16x8 av[2];
        #pragma unroll
        for (int mf = 0; mf < 2; ++mf) {
            const float* p = nodes_b + (size_t)(i0 + wm * 32 + mf * 16 + lrow) * DIM + k0;
            const float4 f1 = *(const float4*)p; const float4 f2 = *(const float4*)(p + 4);
            av[mf][0] = (__bf16)f1.x; av[mf][1] = (__bf16)f1.y;
            av[mf][2] = (__bf16)f1.z; av[mf][3] = (__bf16)f1.w;
            av[mf][4] = (__bf16)f2.x; av[mf][5] = (__bf16)f2.y;
            av[mf][6] = (__bf16)f2.z; av[mf][7] = (__bf16)f2.w;
        }
        bf16x8 bv[4];
        const float* pB = Bm + (size_t)k0 * DIM + d_b0;
        #pragma unroll
        for (int nf = 0; nf < 4; ++nf)
            #pragma unroll
            for (int j = 0; j < 8; ++j) bv[nf][j] = (__bf16)pB[j * DIM + nf * 16];
        #pragma unroll
        for (int mf = 0; mf < 2; ++mf)
            #pragma unroll
            for (int nf = 0; nf < 4; ++nf)
                acc2[mf][nf] = __builtin_amdgcn_mfma_f32_16x16x32_bf16(av[mf], bv[nf], acc2[mf][nf], 0, 0, 0);
    }
    float* out_b = out + (size_t)batch * SEQ * DIM;
    #pragma unroll
    for (int mf = 0; mf < 2; ++mf)
        #pragma unroll
        for (int nf = 0; nf < 4; ++nf) {
            const int col = wn * 64 + nf * 16 + lrow;
            #pragma unroll
            for (int r = 0; r < 4; ++r) {
                const int row = i0 + wm * 32 + mf * 16 + quad * 4 + r;
                const float x = acc2[mf][nf][r];
                out_b[(size_t)row * DIM + col] = (x > 0.0f) ? x : NEG_SLOPE * x;
            }
        }
}

extern "C" void kernel_launch(void* const* d_in, const int* in_sizes, int n_in,
                              void* d_out, int out_size, void* d_ws, size_t ws_size,
                              hipStream_t stream) {
    const float* nodes = (const float*)d_in[0];
    const int*   adj   = (const int*)d_in[1];
    const float* W     = (const float*)d_in[2];
    const float* Bm    = (const float*)d_in[3];
    float*       out   = (float*)d_out;

    const size_t NT_BYTES = (size_t)32 * DIM * SEQ * 2;       // 8388608
    const size_t WB_BYTES = (size_t)DIM * DIM * 2;            // 32768
    const size_t NEED = NT_BYTES + 2 * WB_BYTES;              // 8454144

    if (d_ws != nullptr && ws_size >= NEED) {
        unsigned short* nodesT = (unsigned short*)d_ws;
        unsigned short* WT = (unsigned short*)((char*)d_ws + NT_BYTES);
        unsigned short* BT = (unsigned short*)((char*)d_ws + NT_BYTES + WB_BYTES);
        wb_t<<<dim3(64), dim3(256), 0, stream>>>(W, Bm, WT, BT);
        nodes_t_kernel<<<dim3(512), dim3(256), 0, stream>>>(nodes, nodesT);
        gcn_fused<<<dim3(1024), dim3(256), 0, stream>>>(nodes, adj, nodesT, WT, BT, out);
    } else {
        gcn_fused_fb<<<dim3(512), dim3(256), 0, stream>>>(nodes, adj, W, Bm, out);
    }
}